// Round 5
// baseline (200.312 us; speedup 1.0000x reference)
//
#include <hip/hip_runtime.h>

// ---- problem constants ----
#define Bb 32     // batch
#define NN 1024   // H*W = K dim = output cols per channel
#define CC 128    // channels
#define MT 128    // m-cols per block (4 waves x 32)

typedef __bf16 bf16x8 __attribute__((ext_vector_type(8)));
typedef float f32x16 __attribute__((ext_vector_type(16)));
typedef float f32x4 __attribute__((ext_vector_type(4)));
typedef unsigned short u16x8 __attribute__((ext_vector_type(8)));

// ---------------------------------------------------------------------------
// Pre-pass: inputs [B, N, C] fp32 -> xbf [C, B, N] bf16 (coalesced both sides
// via LDS tile). 512 blocks = 32 b x 16 n-tiles of 64.
// ---------------------------------------------------------------------------
__global__ __launch_bounds__(256) void transpose_x(const float* __restrict__ in,
                                                   __bf16* __restrict__ xbf) {
    __shared__ float tile[64 * 132];  // 64 n x 128 c, row padded to 132 floats
    const int b  = blockIdx.x >> 4;
    const int n0 = (blockIdx.x & 15) << 6;
    const int t  = threadIdx.x;

#pragma unroll
    for (int p = 0; p < 8; ++p) {
        int f     = p * 256 + t;
        int n_off = f >> 5;
        int c4    = (f & 31) << 2;
        f32x4 v = *reinterpret_cast<const f32x4*>(in + ((size_t)(b * NN + n0 + n_off) * CC + c4));
        *reinterpret_cast<f32x4*>(&tile[n_off * 132 + c4]) = v;
    }
    __syncthreads();

    const int c = t >> 1, half = t & 1;
    const size_t obase = ((size_t)c * Bb + b) * NN + n0;
#pragma unroll
    for (int q = 0; q < 4; ++q) {
        int nb = half * 32 + q * 8;
        bf16x8 o;
#pragma unroll
        for (int j = 0; j < 8; ++j) o[j] = (__bf16)tile[(nb + j) * 132 + c];
        *reinterpret_cast<bf16x8*>(xbf + obase + nb) = o;
    }
}

// ---------------------------------------------------------------------------
// Main GEMM — no LDS, no barriers, DEPTH-4 register software pipeline.
// Block = (channel c, m-tile of 128), 4 waves, wave owns 32 m-cols.
// B-fragment: lane reads W[k0+lh*8+e][m=lane&31], per-e the wave touches two
// 128B contiguous row-chunks (coalesced). A-fragment: 16B from xbf[c][b][k].
// Four named buffers (static indexing, no scratch) issue loads 4 units
// (64 k-values) ahead of consumption: issue->use gap ~3 wave-rounds > 900cy
// HBM latency. No barriers => no collective vmcnt drains, waves decorrelate.
// ---------------------------------------------------------------------------
template <int USE_XBF>
__global__ __launch_bounds__(256) void cwdense(const float* __restrict__ W,
                                               const float* __restrict__ bias,
                                               const float* __restrict__ xin,
                                               const __bf16* __restrict__ xbf,
                                               float* __restrict__ out) {
    // XCD mapping: XCD x handles c in [16x,16x+16) for all 8 m-tiles; the 16
    // channel-blocks sharing an output 64B line are concurrent on one XCD.
    const int x     = blockIdx.x;
    const int xcd   = x & 7;
    const int i     = x >> 3;
    const int c     = xcd * 16 + (i & 15);
    const int mtile = i >> 4;
    const int m0    = mtile * MT;

    const int t    = threadIdx.x;
    const int w    = t >> 6;
    const int lane = t & 63;
    const int lm   = lane & 31;   // A row (b) / B col (m) within 32x32 tile
    const int lh   = lane >> 5;   // k half
    const int m    = m0 + w * 32 + lm;

    const float*  wcol = W + (size_t)c * NN * NN + (size_t)(lh * 8) * NN + m;
    const __bf16* xrow = USE_XBF ? (xbf + ((size_t)c * Bb + lm) * NN + lh * 8) : nullptr;

    f32x16 acc;
#pragma unroll
    for (int r = 0; r < 16; ++r) acc[r] = 0.0f;

    float  wvA[8], wvB[8], wvC[8], wvD[8];
    bf16x8 aA, aB, aC, aD;

    auto load_unit = [&](float (&wv)[8], bf16x8& a, int k0) {
#pragma unroll
        for (int e = 0; e < 8; ++e) wv[e] = wcol[(size_t)(k0 + e) * NN];
        if (USE_XBF) {
            a = *reinterpret_cast<const bf16x8*>(xrow + k0);
        } else {
            u16x8 tmp;
#pragma unroll
            for (int e = 0; e < 8; ++e) {
                float f = xin[((size_t)lm * NN + (k0 + lh * 8 + e)) * CC + c];
                unsigned u = __builtin_bit_cast(unsigned, f);
                u = (u + 0x7FFFu + ((u >> 16) & 1u)) >> 16;
                tmp[e] = (unsigned short)u;
            }
            a = __builtin_bit_cast(bf16x8, tmp);
        }
    };

    auto compute_unit = [&](const float (&wv)[8], const bf16x8& a) {
        bf16x8 bfrag;
#pragma unroll
        for (int e = 0; e < 8; ++e) bfrag[e] = (__bf16)wv[e];  // v_cvt_pk_bf16_f32
        acc = __builtin_amdgcn_mfma_f32_32x32x16_bf16(a, bfrag, acc, 0, 0, 0);
    };

    // prologue: 4 units (64 k-values) in flight
    load_unit(wvA, aA, 0);
    load_unit(wvB, aB, 16);
    load_unit(wvC, aC, 32);
    load_unit(wvD, aD, 48);

#pragma unroll 1
    for (int k0 = 0; k0 < NN; k0 += 64) {
        compute_unit(wvA, aA);
        if (k0 + 64 < NN) load_unit(wvA, aA, k0 + 64);
        compute_unit(wvB, aB);
        if (k0 + 80 < NN) load_unit(wvB, aB, k0 + 80);
        compute_unit(wvC, aC);
        if (k0 + 96 < NN) load_unit(wvC, aC, k0 + 96);
        compute_unit(wvD, aD);
        if (k0 + 112 < NN) load_unit(wvD, aD, k0 + 112);
    }

    // epilogue: bias + relu + store. out[b][m][co], co = 127 - c.
    const float bv = bias[(size_t)c * NN + m];
    const int co = (CC - 1) - c;
#pragma unroll
    for (int r = 0; r < 16; ++r) {
        const int brow = (r & 3) + 8 * (r >> 2) + 4 * lh;
        float v = acc[r] + bv;
        v = v > 0.0f ? v : 0.0f;
        out[(size_t)brow * (NN * CC) + (size_t)m * CC + co] = v;
    }
}

extern "C" void kernel_launch(void* const* d_in, const int* in_sizes, int n_in,
                              void* d_out, int out_size, void* d_ws, size_t ws_size,
                              hipStream_t stream) {
    const float* xinp = (const float*)d_in[0];
    const float* W    = (const float*)d_in[1];
    const float* bias = (const float*)d_in[2];
    float* out        = (float*)d_out;

    const size_t need = (size_t)CC * Bb * NN * sizeof(__bf16);  // 8 MB
    if (ws_size >= need) {
        __bf16* xbf = (__bf16*)d_ws;
        transpose_x<<<512, 256, 0, stream>>>(xinp, xbf);
        cwdense<1><<<1024, 256, 0, stream>>>(W, bias, xinp, xbf, out);
    } else {
        cwdense<0><<<1024, 256, 0, stream>>>(W, bias, xinp, nullptr, out);
    }
}

// Round 6
// 153.428 us; speedup vs baseline: 1.3056x; 1.3056x over previous
//
#include <hip/hip_runtime.h>

// ---- problem constants ----
#define Bb 32     // batch
#define NN 1024   // H*W = K dim = output cols per channel
#define CC 128    // channels
#define KS 64     // K step per LDS stage
#define MT 128    // m-cols per block (4 waves x 32)
#define NSTEP (NN / KS)  // 16

typedef __bf16 bf16x8 __attribute__((ext_vector_type(8)));
typedef __bf16 bf16x4 __attribute__((ext_vector_type(4)));
typedef float f32x16 __attribute__((ext_vector_type(16)));
typedef float f32x4 __attribute__((ext_vector_type(4)));
typedef unsigned short u16x8 __attribute__((ext_vector_type(8)));

// ---------------------------------------------------------------------------
// Pre-pass: inputs [B, N, C] fp32 -> xbf [C, B, N] bf16 (coalesced both sides
// via LDS tile). 512 blocks = 32 b x 16 n-tiles of 64.
// ---------------------------------------------------------------------------
__global__ __launch_bounds__(256) void transpose_x(const float* __restrict__ in,
                                                   __bf16* __restrict__ xbf) {
    __shared__ float tile[64 * 132];  // 64 n x 128 c, row padded to 132 floats
    const int b  = blockIdx.x >> 4;
    const int n0 = (blockIdx.x & 15) << 6;
    const int t  = threadIdx.x;

#pragma unroll
    for (int p = 0; p < 8; ++p) {
        int f     = p * 256 + t;
        int n_off = f >> 5;
        int c4    = (f & 31) << 2;
        f32x4 v = *reinterpret_cast<const f32x4*>(in + ((size_t)(b * NN + n0 + n_off) * CC + c4));
        *reinterpret_cast<f32x4*>(&tile[n_off * 132 + c4]) = v;
    }
    __syncthreads();

    const int c = t >> 1, half = t & 1;
    const size_t obase = ((size_t)c * Bb + b) * NN + n0;
#pragma unroll
    for (int q = 0; q < 4; ++q) {
        int nb = half * 32 + q * 8;
        bf16x8 o;
#pragma unroll
        for (int j = 0; j < 8; ++j) o[j] = (__bf16)tile[(nb + j) * 132 + c];
        *reinterpret_cast<bf16x8*>(xbf + obase + nb) = o;
    }
}

// ---------------------------------------------------------------------------
// Main GEMM — R1 skeleton (dwordx4 W staging -> LDS transpose -> MFMA) with
// two surgical fixes:
//   (a) LDS double-buffer: W tile s+2 issued during step s, consumed step s+1
//   (b) barriers never drain vmcnt: lgkmcnt(0)+s_barrier / bare s_barrier
// FIFO order per step: A-loads (young) -> store q [vmcnt(4): waits only the
// 8 W-loads of tile s+1] -> issue W s+2 -> bar -> MFMA [A-wait = vmcnt(8),
// W stays in flight across both barriers]. NO launch-bounds cap (R2/R3's
// 128-VGPR cap serialized/spilled the pipeline).
// ---------------------------------------------------------------------------
template <int USE_XBF>
__global__ __launch_bounds__(256) void cwdense(const float* __restrict__ W,
                                               const float* __restrict__ bias,
                                               const float* __restrict__ xin,
                                               const __bf16* __restrict__ xbf,
                                               float* __restrict__ out) {
    __shared__ __bf16 lds0[MT * 64];  // 16 KB each; [m][kk] swizzled
    __shared__ __bf16 lds1[MT * 64];

    // XCD mapping: XCD x handles c in [16x,16x+16); the 16 blocks sharing an
    // output 64B line (consecutive co) are co-resident on one XCD's L2.
    const int x     = blockIdx.x;
    const int xcd   = x & 7;
    const int i     = x >> 3;
    const int c     = xcd * 16 + (i & 15);
    const int mtile = i >> 4;
    const int m0    = mtile * MT;

    const int t    = threadIdx.x;
    const int w    = t >> 6;
    const int lane = t & 63;
    const int lm   = lane & 31;   // A row (b) / B col (m) within tile
    const int lh   = lane >> 5;   // k half
    const int m_loc = w * 32 + lm;

    const float* wpanel = W + (size_t)c * NN * NN + m0;
    const __bf16* xrow  = USE_XBF ? (xbf + (size_t)(c * Bb + lm) * NN + lh * 8) : nullptr;

    const int mq  = t & 31;    // m quad: cols mq*4..mq*4+3
    const int kq2 = t >> 5;    // kk quads 2*kq2, 2*kq2+1

    f32x16 acc;
#pragma unroll
    for (int r = 0; r < 16; ++r) acc[r] = 0.0f;

    f32x4 q[8];        // W staging (issued step s, stored step s+1)
    bf16x8 af[4];      // A fragments for current step

    auto load_tile = [&](int k0) {
#pragma unroll
        for (int r = 0; r < 8; ++r) {
            const int kk = (kq2 * 2 + (r >> 2)) * 4 + (r & 3);
            q[r] = *reinterpret_cast<const f32x4*>(wpanel + (size_t)(k0 + kk) * NN + mq * 4);
        }
    };

    auto store_tile = [&](__bf16* wl) {
#pragma unroll
        for (int qi = 0; qi < 2; ++qi) {
            const int kkbase = (kq2 * 2 + qi) * 4;
#pragma unroll
            for (int j = 0; j < 4; ++j) {
                const int mm = mq * 4 + j;
                bf16x4 o;
#pragma unroll
                for (int r = 0; r < 4; ++r) o[r] = (__bf16)q[qi * 4 + r][j];
                const int slot = (kkbase >> 3) ^ (mm & 7) ^ ((mm >> 3) & 7);
                *reinterpret_cast<bf16x4*>(&wl[mm * 64 + slot * 8 + (kkbase & 7)]) = o;
            }
        }
    };

    auto load_a = [&](int k0) {
        if (USE_XBF) {
#pragma unroll
            for (int mi = 0; mi < 4; ++mi)
                af[mi] = *reinterpret_cast<const bf16x8*>(xrow + k0 + mi * 16);
        } else {
#pragma unroll
            for (int mi = 0; mi < 4; ++mi) {
                u16x8 tmp;
#pragma unroll
                for (int e = 0; e < 8; ++e) {
                    float f = xin[((size_t)lm * NN + (k0 + mi * 16 + lh * 8 + e)) * CC + c];
                    unsigned u = __builtin_bit_cast(unsigned, f);
                    u = (u + 0x7FFFu + ((u >> 16) & 1u)) >> 16;
                    tmp[e] = (unsigned short)u;
                }
                af[mi] = __builtin_bit_cast(bf16x8, tmp);
            }
        }
    };

    auto mfma_step = [&](const __bf16* wl) {
#pragma unroll
        for (int mi = 0; mi < 4; ++mi) {
            const int kk = mi * 16 + lh * 8;
            const int slot = (kk >> 3) ^ (m_loc & 7) ^ ((m_loc >> 3) & 7);
            bf16x8 bfrag = *reinterpret_cast<const bf16x8*>(&wl[m_loc * 64 + slot * 8]);
            acc = __builtin_amdgcn_mfma_f32_32x32x16_bf16(af[mi], bfrag, acc, 0, 0, 0);
        }
    };

#define BAR_LGKM0()                                           \
    asm volatile("s_waitcnt lgkmcnt(0)" ::: "memory");        \
    __builtin_amdgcn_s_barrier()
#define BAR_PLAIN() __builtin_amdgcn_s_barrier()

    // prologue: W0 -> lds0; W1 in flight in q
    load_tile(0);
    store_tile(lds0);
    load_tile(1 * KS);

#pragma unroll 1
    for (int s = 0; s < NSTEP; s += 2) {
        // ---- even step s: compute lds0 (tile s); store W_{s+1} -> lds1 ----
        load_a(s * KS);                                   // young in FIFO
        store_tile(lds1);                                 // waits vmcnt(4): W_{s+1} only
        if (s + 2 < NSTEP) load_tile((s + 2) * KS);       // W_{s+2} issue
        BAR_LGKM0();                                      // flush ds_writes; no vm drain
        mfma_step(lds0);                                  // A-wait vmcnt(8): W flying
        BAR_PLAIN();                                      // lds0 reads done before next store

        // ---- odd step s+1: compute lds1 (tile s+1); store W_{s+2} -> lds0 ----
        load_a((s + 1) * KS);
        if (s + 2 < NSTEP) store_tile(lds0);
        if (s + 3 < NSTEP) load_tile((s + 3) * KS);
        BAR_LGKM0();
        mfma_step(lds1);
        BAR_PLAIN();
    }
#undef BAR_LGKM0
#undef BAR_PLAIN

    // epilogue: bias + relu + store. out[b][m][co], co = 127 - c.
    const int m  = m0 + m_loc;
    const float bv = bias[(size_t)c * NN + m];
    const int co = (CC - 1) - c;
#pragma unroll
    for (int r = 0; r < 16; ++r) {
        const int brow = (r & 3) + 8 * (r >> 2) + 4 * lh;
        float v = acc[r] + bv;
        v = v > 0.0f ? v : 0.0f;
        out[(size_t)brow * (NN * CC) + (size_t)m * CC + co] = v;
    }
}

extern "C" void kernel_launch(void* const* d_in, const int* in_sizes, int n_in,
                              void* d_out, int out_size, void* d_ws, size_t ws_size,
                              hipStream_t stream) {
    const float* xinp = (const float*)d_in[0];
    const float* W    = (const float*)d_in[1];
    const float* bias = (const float*)d_in[2];
    float* out        = (float*)d_out;

    const size_t need = (size_t)CC * Bb * NN * sizeof(__bf16);  // 8 MB
    if (ws_size >= need) {
        __bf16* xbf = (__bf16*)d_ws;
        transpose_x<<<512, 256, 0, stream>>>(xinp, xbf);
        cwdense<1><<<1024, 256, 0, stream>>>(W, bias, xinp, xbf, out);
    } else {
        cwdense<0><<<1024, 256, 0, stream>>>(W, bias, xinp, nullptr, out);
    }
}

// Round 7
// 146.375 us; speedup vs baseline: 1.3685x; 1.0482x over previous
//
#include <hip/hip_runtime.h>

// ---- problem constants ----
#define Bb 32     // batch (GEMM M)
#define NN 1024   // H*W = K dim = output cols per channel
#define CC 128    // channels
#define KC 4      // K-chunks per channel (256 k each)

typedef __bf16 bf16x8 __attribute__((ext_vector_type(8)));
typedef float f32x16 __attribute__((ext_vector_type(16)));
typedef float f32x4 __attribute__((ext_vector_type(4)));
typedef float f32x2 __attribute__((ext_vector_type(2)));

// ---------------------------------------------------------------------------
// Kernel A: inputs [B,N,C] f32 -> xfrag[c][ku][lane][e] bf16 (8 MB), the exact
// mfma_32x32x16 A-fragment order: lane l, elem e of k-unit ku holds
// x[b=l&31][k=ku*16+8*(l>>5)+e][c]. GEMM A-loads become ONE coalesced dwordx4.
// Grid 256 = ku(64) x c-group(4 of 32). 256 threads.
// ---------------------------------------------------------------------------
__global__ __launch_bounds__(256) void build_xfrag(const float* __restrict__ in,
                                                   __bf16* __restrict__ xfrag) {
    __shared__ float t32[16 * 32 * 34];  // [kk][b][cc] stride 34 (68 KB)
    const int ku = blockIdx.x >> 2;
    const int c0 = (blockIdx.x & 3) * 32;
    const int t  = threadIdx.x;

    // load 16k x 32b x 32c tile, 128-B runs
#pragma unroll
    for (int p = 0; p < 16; ++p) {
        int U   = p * 256 + t;
        int row = U >> 3;          // 0..511 = b*16 + kk
        int b   = row >> 4, kk = row & 15;
        int cg  = (U & 7) * 4;
        f32x4 v = *reinterpret_cast<const f32x4*>(
            in + ((size_t)(b * NN + ku * 16 + kk) * CC) + c0 + cg);
        int base = (kk * 32 + b) * 34 + cg;
        *reinterpret_cast<f32x2*>(&t32[base])     = f32x2{v[0], v[1]};
        *reinterpret_cast<f32x2*>(&t32[base + 2]) = f32x2{v[2], v[3]};
    }
    __syncthreads();

    // emit: thread t -> cc = t&31, lane-group = t>>5 (8 lanes), 8 e each
    const int cc = t & 31, lgrp = t >> 5;
    __bf16* dst = xfrag + ((size_t)(c0 + cc) * 64 + ku) * 512;
#pragma unroll
    for (int li = 0; li < 8; ++li) {
        int l = lgrp * 8 + li;
        int b = l & 31, kk0 = (l >> 5) * 8;
        bf16x8 o;
#pragma unroll
        for (int e = 0; e < 8; ++e) o[e] = (__bf16)t32[((kk0 + e) * 32 + b) * 34 + cc];
        *reinterpret_cast<bf16x8*>(dst + l * 8) = o;
    }
}

// ---------------------------------------------------------------------------
// Kernel B: partial GEMM. Block = (channel c, k-chunk kc of 256 k), ALL 1024 m.
// W read = 1 MB CONTIGUOUS per block (64-KB linear chunk per step) -- the H1
// test. 512 threads / 8 waves; wave owns 128 m = 4 MFMA column-tiles.
// LDS: lane-linear fragment layout [mt][lane][e] (reads conflict-free),
// double-buffered 2x32 KB, one __syncthreads per step (dbuf makes the second
// barrier unnecessary). Partials part[kc][c][b][m] f32 -> ws.
// ---------------------------------------------------------------------------
__global__ __launch_bounds__(512) void gemm_part(const float* __restrict__ W,
                                                 const __bf16* __restrict__ xfrag,
                                                 float* __restrict__ part) {
    __shared__ __bf16 buf0[32 * 512];  // 32 KB: 32 m-tiles x 64 lanes x 8 e
    __shared__ __bf16 buf1[32 * 512];

    const int c  = blockIdx.x >> 2;
    const int kc = blockIdx.x & 3;
    const int t    = threadIdx.x;
    const int w    = t >> 6;
    const int lane = t & 63;

    const float* Wc = W + (size_t)c * NN * NN + (size_t)kc * 256 * NN;
    const __bf16* xline = xfrag + ((size_t)c * 64 + kc * 16) * 512 + lane * 8;

    const int m4  = t & 255;   // m-quad: m = m4*4..+3
    const int lhs = t >> 8;    // k-oct: rows lhs*8..+7 of each 16-k step
    const int mts = m4 >> 3;   // staging m-tile (const over i)

    f32x16 acc[4];
#pragma unroll
    for (int mi = 0; mi < 4; ++mi)
#pragma unroll
        for (int r = 0; r < 16; ++r) acc[mi][r] = 0.0f;

    f32x4 q[8];
    bf16x8 aA, aB;

    auto load_w = [&](int s) {
        const float* p = Wc + (size_t)(s * 16 + lhs * 8) * NN + m4 * 4;
#pragma unroll
        for (int j = 0; j < 8; ++j)
            q[j] = *reinterpret_cast<const f32x4*>(p + (size_t)j * NN);
    };
    auto load_a = [&](int s) {
        return *reinterpret_cast<const bf16x8*>(xline + (size_t)s * 512);
    };
    auto store_t = [&](__bf16* b_) {
#pragma unroll
        for (int i = 0; i < 4; ++i) {
            const int m = m4 * 4 + i;
            const int lidx = (m & 31) + (lhs << 5);
            bf16x8 o;
#pragma unroll
            for (int j = 0; j < 8; ++j) o[j] = (__bf16)q[j][i];
            const int u = (mts * 512 + lidx * 8) ^ ((mts & 7) << 3);
            *reinterpret_cast<bf16x8*>(&b_[u]) = o;  // b128, 16-B aligned
        }
    };
    auto mfma4 = [&](const __bf16* b_, bf16x8 a) {
#pragma unroll
        for (int mi = 0; mi < 4; ++mi) {
            const int mt = w * 4 + mi;
            const int u = (mt * 512 + lane * 8) ^ ((mt & 7) << 3);
            bf16x8 f = *reinterpret_cast<const bf16x8*>(&b_[u]);
            acc[mi] = __builtin_amdgcn_mfma_f32_32x32x16_bf16(a, f, acc[mi], 0, 0, 0);
        }
    };

    load_w(0);
    aA = load_a(0);

#pragma unroll 1
    for (int su = 0; su < 8; ++su) {
        const int s = su * 2;
        // even sub-step: tile s (in q) -> buf0
        store_t(buf0);
        load_w(s + 1);
        aB = load_a(s + 1);
        __syncthreads();
        mfma4(buf0, aA);
        // odd sub-step: tile s+1 -> buf1
        store_t(buf1);
        if (s + 2 < 16) { load_w(s + 2); aA = load_a(s + 2); }
        __syncthreads();
        mfma4(buf1, aB);
    }

    // partials: part[kc][c][b][m], 128-B runs per store instr, waves cover all m
    float* pc = part + (size_t)(kc * CC + c) * Bb * NN;
#pragma unroll
    for (int mi = 0; mi < 4; ++mi) {
        const int m = w * 128 + mi * 32 + (lane & 31);
#pragma unroll
        for (int r = 0; r < 16; ++r) {
            const int brow = (r & 3) + 8 * (r >> 2) + 4 * (lane >> 5);
            pc[(size_t)brow * NN + m] = acc[mi][r];
        }
    }
}

// ---------------------------------------------------------------------------
// Kernel C: reduce 4 partials + bias + relu + reversed-channel permute.
// Grid 512 = b(32) x m-tile(16 of 64). LDS-transposed so both the partial
// reads (m-fast, 256-B runs) and output writes (co-fast, 512-B runs) coalesce.
// ---------------------------------------------------------------------------
__global__ __launch_bounds__(256) void reduce_out(const float* __restrict__ part,
                                                  const float* __restrict__ bias,
                                                  float* __restrict__ out) {
    __shared__ float st[CC * 65];  // [c][mm] pad 65 (33 KB)
    const int b  = blockIdx.x >> 4;
    const int m0 = (blockIdx.x & 15) * 64;
    const int t  = threadIdx.x;

    {
        const int mm = t & 63, cr = t >> 6;
#pragma unroll 4
        for (int j = 0; j < 32; ++j) {
            const int c = cr * 32 + j;
            const size_t base = ((size_t)c * Bb + b) * NN + m0 + mm;
            const size_t kstep = (size_t)CC * Bb * NN;  // 4 M elems
            float s = part[base] + part[base + kstep] +
                      part[base + 2 * kstep] + part[base + 3 * kstep];
            s += bias[(size_t)c * NN + m0 + mm];
            st[c * 65 + mm] = s > 0.0f ? s : 0.0f;
        }
    }
    __syncthreads();
    {
        const int co4 = (t & 31) * 4, mr = t >> 5;
#pragma unroll
        for (int jj = 0; jj < 8; ++jj) {
            const int mloc = mr + 8 * jj;
            f32x4 v;
#pragma unroll
            for (int i = 0; i < 4; ++i)
                v[i] = st[(CC - 1 - co4 - i) * 65 + mloc];
            *reinterpret_cast<f32x4*>(out + ((size_t)b * NN + m0 + mloc) * CC + co4) = v;
        }
    }
}

extern "C" void kernel_launch(void* const* d_in, const int* in_sizes, int n_in,
                              void* d_out, int out_size, void* d_ws, size_t ws_size,
                              hipStream_t stream) {
    const float* xinp = (const float*)d_in[0];
    const float* W    = (const float*)d_in[1];
    const float* bias = (const float*)d_in[2];
    float* out        = (float*)d_out;

    __bf16* xfrag = (__bf16*)d_ws;                                   // 8 MB
    float*  part  = (float*)((char*)d_ws + (size_t)8 * 1024 * 1024); // 64 MB

    build_xfrag<<<256, 256, 0, stream>>>(xinp, xfrag);
    gemm_part<<<512, 512, 0, stream>>>(W, xfrag, part);
    reduce_out<<<512, 256, 0, stream>>>(part, bias, out);
}

// Round 8
// 109.542 us; speedup vs baseline: 1.8286x; 1.3362x over previous
//
#include <hip/hip_runtime.h>

// ---- problem constants ----
#define Bb 32     // batch
#define NN 1024   // H*W = K dim = output cols per channel
#define CC 128    // channels
#define KS 64     // K step per LDS stage
#define MT 128    // m-cols per block (4 waves x 32)
#define NSTEP (NN / KS)  // 16

typedef __bf16 bf16x8 __attribute__((ext_vector_type(8)));
typedef __bf16 bf16x4 __attribute__((ext_vector_type(4)));
typedef float f32x16 __attribute__((ext_vector_type(16)));
typedef float f32x4 __attribute__((ext_vector_type(4)));
typedef unsigned short u16x8 __attribute__((ext_vector_type(8)));

// ---------------------------------------------------------------------------
// Pre-pass: inputs [B, N, C] fp32 -> xbf [C, B, N] bf16. Unchanged from R1.
// ---------------------------------------------------------------------------
__global__ __launch_bounds__(256) void transpose_x(const float* __restrict__ in,
                                                   __bf16* __restrict__ xbf) {
    __shared__ float tile[64 * 132];
    const int b  = blockIdx.x >> 4;
    const int n0 = (blockIdx.x & 15) << 6;
    const int t  = threadIdx.x;

#pragma unroll
    for (int p = 0; p < 8; ++p) {
        int f     = p * 256 + t;
        int n_off = f >> 5;
        int c4    = (f & 31) << 2;
        f32x4 v = *reinterpret_cast<const f32x4*>(in + ((size_t)(b * NN + n0 + n_off) * CC + c4));
        *reinterpret_cast<f32x4*>(&tile[n_off * 132 + c4]) = v;
    }
    __syncthreads();

    const int c = t >> 1, half = t & 1;
    const size_t obase = ((size_t)c * Bb + b) * NN + n0;
#pragma unroll
    for (int q = 0; q < 4; ++q) {
        int nb = half * 32 + q * 8;
        bf16x8 o;
#pragma unroll
        for (int j = 0; j < 8; ++j) o[j] = (__bf16)tile[(nb + j) * 132 + c];
        *reinterpret_cast<bf16x8*>(xbf + obase + nb) = o;
    }
}

// ---------------------------------------------------------------------------
// Main GEMM — EXACT R1 loop (best known: 134.7us). Only the data paths differ:
//  * W loads are non-temporal (512-MB single-use stream, skip L2 allocation)
//  * epilogue writes part[c][b][m] (block-private, linear, full 64-B lines:
//    no inter-block line sharing -> no RFO/partial-evict write amplification)
// ---------------------------------------------------------------------------
__global__ __launch_bounds__(256) void cwdense_part(const float* __restrict__ W,
                                                    const float* __restrict__ bias,
                                                    const __bf16* __restrict__ xbf,
                                                    float* __restrict__ part) {
    __shared__ __bf16 wlds[MT * 64];  // 16 KB, row = 64 bf16 = 128 B

    const int x     = blockIdx.x;
    const int xcd   = x & 7;
    const int i     = x >> 3;
    const int c     = xcd * 16 + (i & 15);
    const int mtile = i >> 4;
    const int m0    = mtile * MT;

    const int t    = threadIdx.x;
    const int w    = t >> 6;
    const int lane = t & 63;
    const int lm   = lane & 31;
    const int lh   = lane >> 5;
    const int m_loc = w * 32 + lm;

    const float* wpanel = W + (size_t)c * NN * NN + m0;
    const __bf16* xrow  = xbf + (size_t)(c * Bb + lm) * NN;

    const int mq  = t & 31;
    const int kq2 = t >> 5;

    f32x16 acc;
#pragma unroll
    for (int r = 0; r < 16; ++r) acc[r] = 0.0f;

    for (int step = 0; step < NSTEP; ++step) {
        const int k0 = step * KS;

        // coalesced nt global loads: 8 x dwordx4 per thread
        f32x4 q[2][4];
#pragma unroll
        for (int qi = 0; qi < 2; ++qi)
#pragma unroll
            for (int r = 0; r < 4; ++r)
                q[qi][r] = __builtin_nontemporal_load(reinterpret_cast<const f32x4*>(
                    wpanel + (size_t)(k0 + (kq2 * 2 + qi) * 4 + r) * NN + mq * 4));

        __syncthreads();  // previous step's B-frag reads done before overwrite

        // in-register 4x4 transpose -> bf16 -> swizzled LDS [m][kk]
#pragma unroll
        for (int qi = 0; qi < 2; ++qi) {
            const int kkbase = (kq2 * 2 + qi) * 4;
#pragma unroll
            for (int j = 0; j < 4; ++j) {
                const int m = mq * 4 + j;
                bf16x4 o;
#pragma unroll
                for (int r = 0; r < 4; ++r) o[r] = (__bf16)q[qi][r][j];
                const int slot = (kkbase >> 3) ^ (m & 7) ^ ((m >> 3) & 7);
                *reinterpret_cast<bf16x4*>(&wlds[m * 64 + slot * 8 + (kkbase & 7)]) = o;
            }
        }
        __syncthreads();

        // 4 MFMAs covering KS=64
#pragma unroll
        for (int mi = 0; mi < 4; ++mi) {
            const int kk = mi * 16 + lh * 8;
            bf16x8 a = *reinterpret_cast<const bf16x8*>(xrow + k0 + kk);
            const int slot = (kk >> 3) ^ (m_loc & 7) ^ ((m_loc >> 3) & 7);
            bf16x8 bfrag = *reinterpret_cast<const bf16x8*>(&wlds[m_loc * 64 + slot * 8]);
            acc = __builtin_amdgcn_mfma_f32_32x32x16_bf16(a, bfrag, acc, 0, 0, 0);
        }
    }

    // epilogue: bias + relu -> part[c][b][m], block-private linear full lines
    const int m  = m0 + m_loc;
    const float bv = bias[(size_t)c * NN + m];
    float* pc = part + (size_t)c * Bb * NN;
#pragma unroll
    for (int r = 0; r < 16; ++r) {
        const int brow = (r & 3) + 8 * (r >> 2) + 4 * lh;
        float v = acc[r] + bv;
        v = v > 0.0f ? v : 0.0f;
        pc[(size_t)brow * NN + m] = v;
    }
}

// ---------------------------------------------------------------------------
// Permute pass: part[c][b][m] -> out[b][m][co], co = 127 - c. LDS-transposed
// so reads are 256-B c-major runs and writes are full f32x4 lines (pattern
// validated in R7's reduce_out). Grid 512 = b(32) x m-tile(16 of 64).
// ---------------------------------------------------------------------------
__global__ __launch_bounds__(256) void permute_out(const float* __restrict__ part,
                                                   float* __restrict__ out) {
    __shared__ float st[CC * 65];  // [c][mm], pad 65
    const int b  = blockIdx.x >> 4;
    const int m0 = (blockIdx.x & 15) * 64;
    const int t  = threadIdx.x;

    {
        const int mm = t & 63, cr = t >> 6;
#pragma unroll 4
        for (int j = 0; j < 32; ++j) {
            const int c = cr * 32 + j;
            st[c * 65 + mm] = part[((size_t)c * Bb + b) * NN + m0 + mm];
        }
    }
    __syncthreads();
    {
        const int co4 = (t & 31) * 4, mr = t >> 5;
#pragma unroll
        for (int jj = 0; jj < 8; ++jj) {
            const int mloc = mr + 8 * jj;
            f32x4 v;
#pragma unroll
            for (int i = 0; i < 4; ++i)
                v[i] = st[(CC - 1 - co4 - i) * 65 + mloc];
            __builtin_nontemporal_store(v, reinterpret_cast<f32x4*>(
                out + ((size_t)b * NN + m0 + mloc) * CC + co4));
        }
    }
}

// ---------------------------------------------------------------------------
// Fallback (ws too small): R1's direct-out kernel, verbatim.
// ---------------------------------------------------------------------------
template <int USE_XBF>
__global__ __launch_bounds__(256) void cwdense_direct(const float* __restrict__ W,
                                                      const float* __restrict__ bias,
                                                      const float* __restrict__ xin,
                                                      const __bf16* __restrict__ xbf,
                                                      float* __restrict__ out) {
    __shared__ __bf16 wlds[MT * 64];
    const int x = blockIdx.x, xcd = x & 7, i = x >> 3;
    const int c = xcd * 16 + (i & 15), mtile = i >> 4, m0 = mtile * MT;
    const int t = threadIdx.x, w = t >> 6, lane = t & 63;
    const int lm = lane & 31, lh = lane >> 5, m_loc = w * 32 + lm;
    const float* wpanel = W + (size_t)c * NN * NN + m0;
    const int mq = t & 31, kq2 = t >> 5;

    f32x16 acc;
#pragma unroll
    for (int r = 0; r < 16; ++r) acc[r] = 0.0f;

    for (int step = 0; step < NSTEP; ++step) {
        const int k0 = step * KS;
        f32x4 q[2][4];
#pragma unroll
        for (int qi = 0; qi < 2; ++qi)
#pragma unroll
            for (int r = 0; r < 4; ++r)
                q[qi][r] = *reinterpret_cast<const f32x4*>(
                    wpanel + (size_t)(k0 + (kq2 * 2 + qi) * 4 + r) * NN + mq * 4);
        __syncthreads();
#pragma unroll
        for (int qi = 0; qi < 2; ++qi) {
            const int kkbase = (kq2 * 2 + qi) * 4;
#pragma unroll
            for (int j = 0; j < 4; ++j) {
                const int m = mq * 4 + j;
                bf16x4 o;
#pragma unroll
                for (int r = 0; r < 4; ++r) o[r] = (__bf16)q[qi][r][j];
                const int slot = (kkbase >> 3) ^ (m & 7) ^ ((m >> 3) & 7);
                *reinterpret_cast<bf16x4*>(&wlds[m * 64 + slot * 8 + (kkbase & 7)]) = o;
            }
        }
        __syncthreads();
#pragma unroll
        for (int mi = 0; mi < 4; ++mi) {
            const int kk = mi * 16 + lh * 8;
            bf16x8 a;
            if (USE_XBF) {
                a = *reinterpret_cast<const bf16x8*>(xbf + ((size_t)(c * Bb + lm) * NN + k0 + kk));
            } else {
                u16x8 tmp;
#pragma unroll
                for (int e = 0; e < 8; ++e) {
                    float f = xin[((size_t)lm * NN + (k0 + kk + e)) * CC + c];
                    unsigned u = __builtin_bit_cast(unsigned, f);
                    u = (u + 0x7FFFu + ((u >> 16) & 1u)) >> 16;
                    tmp[e] = (unsigned short)u;
                }
                a = __builtin_bit_cast(bf16x8, tmp);
            }
            const int slot = (kk >> 3) ^ (m_loc & 7) ^ ((m_loc >> 3) & 7);
            bf16x8 bfrag = *reinterpret_cast<const bf16x8*>(&wlds[m_loc * 64 + slot * 8]);
            acc = __builtin_amdgcn_mfma_f32_32x32x16_bf16(a, bfrag, acc, 0, 0, 0);
        }
    }
    const int m = m0 + m_loc;
    const float bv = bias[(size_t)c * NN + m];
    const int co = (CC - 1) - c;
#pragma unroll
    for (int r = 0; r < 16; ++r) {
        const int brow = (r & 3) + 8 * (r >> 2) + 4 * lh;
        float v = acc[r] + bv;
        v = v > 0.0f ? v : 0.0f;
        out[(size_t)brow * (NN * CC) + (size_t)m * CC + co] = v;
    }
}

extern "C" void kernel_launch(void* const* d_in, const int* in_sizes, int n_in,
                              void* d_out, int out_size, void* d_ws, size_t ws_size,
                              hipStream_t stream) {
    const float* xinp = (const float*)d_in[0];
    const float* W    = (const float*)d_in[1];
    const float* bias = (const float*)d_in[2];
    float* out        = (float*)d_out;

    const size_t part_bytes = (size_t)CC * Bb * NN * sizeof(float);   // 16 MB
    const size_t xbf_bytes  = (size_t)CC * Bb * NN * sizeof(__bf16);  // 8 MB

    if (ws_size >= part_bytes + xbf_bytes) {
        float*  part = (float*)d_ws;
        __bf16* xbf  = (__bf16*)((char*)d_ws + part_bytes);
        transpose_x<<<512, 256, 0, stream>>>(xinp, xbf);
        cwdense_part<<<1024, 256, 0, stream>>>(W, bias, xbf, part);
        permute_out<<<512, 256, 0, stream>>>(part, out);
    } else if (ws_size >= xbf_bytes) {
        __bf16* xbf = (__bf16*)d_ws;
        transpose_x<<<512, 256, 0, stream>>>(xinp, xbf);
        cwdense_direct<1><<<1024, 256, 0, stream>>>(W, bias, xinp, xbf, out);
    } else {
        cwdense_direct<0><<<1024, 256, 0, stream>>>(W, bias, xinp, nullptr, out);
    }
}